// Round 6
// baseline (214.634 us; speedup 1.0000x reference)
//
#include <hip/hip_runtime.h>

// FlowGNN R5: DIAGNOSTIC ROUND — 3 dispatches (gather-only, gemm-only, full).
// R1(branchy)/R2(predicated)/R3(pipelined) all hit 51-58us with L3-resident
// data. VGPR=32..40 proves the compiler chunked the gather to a few
// outstanding loads (register-minimizing), exposing serial L3 latency per j.
// Fix under test: inline-asm saddr-form global_load_dword into 33 forced
// registers (full-row per instruction), single vmcnt(0) per j.
#define DEG   32
#define F_IN  64
#define F_H   128
#define F_OUT 64
#define NW    8
#define BLOCK (NW * 64)

// MODE: 0 = full (writes out), 1 = gather-only (ws), 2 = gemm-only (ws)
template <int MODE>
__launch_bounds__(BLOCK, 8)   // VGPR <= 64 -> 32 waves/CU
__global__ void fg_kernel(const float* __restrict__ x,
                          const float* __restrict__ times,
                          const float* __restrict__ ts,
                          const float* __restrict__ W0,
                          const float* __restrict__ b0,
                          const float* __restrict__ W1,
                          const float* __restrict__ b1,
                          const int*   __restrict__ batch,
                          const int*   __restrict__ idx,
                          float*       __restrict__ out,
                          float*       __restrict__ ws)
{
    // LDS pool with phase overlays (39472 B -> 4 blocks/CU capacity)
    __shared__ __align__(16) float smem[9868];
    float*    W0s     = smem;                       // [8192]
    int*      idx_s   = (int*)(smem + 8192);        // [33*32]
    float*    t2_s    = smem + 9248;                // [33]
    int*      nodes_s = (int*)(smem + 9284);        // [33]
    unsigned* mask_s  = (unsigned*)(smem + 9320);   // [33]
    float*    meanw   = smem + 9356;                // [NW*64]
    // phase 2 overlay: red = smem[0..1024), aggm = smem[1024..1152)

    const int b    = blockIdx.x;
    const int t    = threadIdx.x;
    const int wid  = t >> 6;
    const int lane = t & 63;

    const int   node0 = batch[b];
    const float tb    = times[b];

    if (t < DEG) {
        t2_s[t]    = ts [node0 * DEG + t];
        nodes_s[t] = idx[node0 * DEG + t];
    }
    if (t == DEG) { t2_s[DEG] = tb; nodes_s[DEG] = node0; }
    __syncthreads();

    {   // stage W0 (coalesced float4)
        const float4* src = (const float4*)W0;
        float4*       dst = (float4*)W0s;
        #pragma unroll
        for (int i = t; i < (F_IN * F_H) / 4; i += BLOCK) dst[i] = src[i];
    }
    // stage all frontier neighbor ids + temporal masks
    #pragma unroll
    for (int q = 0; q < 3; ++q) {
        const int p = t + q * BLOCK;           // pair index -> (j = p>>5, d = p&31)
        bool bit = false;
        if (p < (DEG + 1) * DEG) {
            const int j = p >> 5, d = p & 31;
            const int nd = nodes_s[j];
            idx_s[p] = idx[nd * DEG + d];
            bit = (ts[nd * DEG + d] <= t2_s[j]);
        }
        const unsigned long long bal = __ballot(bit);
        const int prow = (q * BLOCK + (t & ~63)) >> 5;
        if (p < (DEG + 1) * DEG) {
            if (lane == 0)  mask_s[prow]     = (unsigned)(bal & 0xffffffffULL);
            if (lane == 32) mask_s[prow + 1] = (unsigned)(bal >> 32);
        }
    }
    __syncthreads();

    const unsigned long long liveM =
        __ballot((lane <= DEG) ? (t2_s[lane] <= tb) : false);

    const float b0x = b0[2 * lane];
    const float b0y = b0[2 * lane + 1];
    float a1x = 0.f, a1y = 0.f;

    for (int j = wid; j <= DEG; j += NW) {
        if (!((liveM >> j) & 1ULL)) continue;

        if constexpr (MODE != 2) {
            // lane n<32 holds neighbor-id n, lanes>=32 hold self id (readlane 32)
            int vid = (lane < DEG) ? idx_s[j * DEG + lane] : nodes_s[j];
            const unsigned ms   = __builtin_amdgcn_readfirstlane(mask_s[j]);
            const unsigned voff = (unsigned)(lane * 4);   // byte offset in row

            // Forced-MLP gather: 33 saddr-form row loads issued back-to-back
            // (volatile asm = fixed order, no interleaved waits), then ONE wait.
            float v[DEG + 1];
            #pragma unroll
            for (int n = 0; n <= DEG; ++n) {
                const int rid = __builtin_amdgcn_readlane(vid, (n < DEG) ? n : DEG);
                const char* base = (const char*)x + ((size_t)(unsigned)rid << 8); // rid*256B
                asm volatile("global_load_dword %0, %1, %2"
                             : "=v"(v[n]) : "v"(voff), "s"(base));
            }
            asm volatile("s_waitcnt vmcnt(0)" ::: "memory");
            __builtin_amdgcn_sched_barrier(0);            // rule 18: pin consumers below

            float acc = v[DEG];                           // self row
            #pragma unroll
            for (int n = 0; n < DEG; ++n)
                acc += ((ms >> n) & 1u) ? v[n] : 0.f;     // reference sum order
            meanw[wid * F_IN + lane] =
                acc * __builtin_amdgcn_rcpf((float)(__popc(ms) + 1));
        } else {
            meanw[wid * F_IN + lane] = (float)(j + 1) * 0.03125f + (float)lane * 0.001f;
        }

        if constexpr (MODE != 1) {
            float hx = 0.f, hy = 0.f;
            #pragma unroll
            for (int f4 = 0; f4 < F_IN / 4; ++f4) {
                const float4 m4 = *(const float4*)&meanw[wid * F_IN + 4 * f4];
                const float2 wa = *(const float2*)&W0s[(4 * f4 + 0) * F_H + 2 * lane];
                const float2 wb = *(const float2*)&W0s[(4 * f4 + 1) * F_H + 2 * lane];
                const float2 wc = *(const float2*)&W0s[(4 * f4 + 2) * F_H + 2 * lane];
                const float2 wd = *(const float2*)&W0s[(4 * f4 + 3) * F_H + 2 * lane];
                hx += m4.x * wa.x; hy += m4.x * wa.y;
                hx += m4.y * wb.x; hy += m4.y * wb.y;
                hx += m4.z * wc.x; hy += m4.z * wc.y;
                hx += m4.w * wd.x; hy += m4.w * wd.y;
            }
            a1x += fmaxf(hx + b0x, 0.f);
            a1y += fmaxf(hy + b0y, 0.f);
        } else {
            a1x += meanw[wid * F_IN + lane];              // keep gather live (rule 17)
        }
    }

    if constexpr (MODE == 1) {
        ws[(size_t)(b & 255) * BLOCK + t] = a1x;          // liveness sink (<=512KB)
        return;
    }

    __syncthreads();
    float* red  = smem;                                   // overlay W0s
    float* aggm = smem + NW * F_H;
    red[wid * F_H + 2 * lane]     = a1x;
    red[wid * F_H + 2 * lane + 1] = a1y;
    __syncthreads();

    if (wid == 0) {
        const float cnt1 = (float)__popcll(liveM);
        float sx = 0.f, sy = 0.f;
        #pragma unroll
        for (int w = 0; w < NW; ++w) {
            sx += red[w * F_H + 2 * lane];
            sy += red[w * F_H + 2 * lane + 1];
        }
        aggm[2 * lane]     = sx / cnt1;
        aggm[2 * lane + 1] = sy / cnt1;

        float o = b1[lane];
        #pragma unroll
        for (int k4 = 0; k4 < F_H / 4; ++k4) {
            const float4 a4 = *(const float4*)&aggm[4 * k4];
            o += a4.x * W1[(4 * k4 + 0) * F_OUT + lane];
            o += a4.y * W1[(4 * k4 + 1) * F_OUT + lane];
            o += a4.z * W1[(4 * k4 + 2) * F_OUT + lane];
            o += a4.w * W1[(4 * k4 + 3) * F_OUT + lane];
        }
        if constexpr (MODE == 0)
            out[b * F_OUT + lane] = fmaxf(o, 0.f);
        else
            ws[131072 + (size_t)(b & 255) * F_OUT + lane] = fmaxf(o, 0.f);
    }
}

extern "C" void kernel_launch(void* const* d_in, const int* in_sizes, int n_in,
                              void* d_out, int out_size, void* d_ws, size_t ws_size,
                              hipStream_t stream)
{
    const float* x     = (const float*)d_in[0];
    const float* times = (const float*)d_in[1];
    const float* ts    = (const float*)d_in[2];
    const float* W0    = (const float*)d_in[3];
    const float* b0    = (const float*)d_in[4];
    const float* W1    = (const float*)d_in[5];
    const float* b1    = (const float*)d_in[6];
    const int*   batch = (const int*)d_in[7];
    const int*   idx   = (const int*)d_in[8];
    float*       out   = (float*)d_out;
    float*       ws    = (float*)d_ws;

    const int B = in_sizes[1];   // 2048 queries

    // Diagnostic dispatches (skipped only if ws is too small; deterministic).
    if (ws_size >= (size_t)(131072 + 256 * F_OUT) * sizeof(float)) {
        fg_kernel<1><<<B, BLOCK, 0, stream>>>(x, times, ts, W0, b0, W1, b1, batch, idx, out, ws);
        fg_kernel<2><<<B, BLOCK, 0, stream>>>(x, times, ts, W0, b0, W1, b1, batch, idx, out, ws);
    }
    // Full fused kernel — the only writer of d_out.
    fg_kernel<0><<<B, BLOCK, 0, stream>>>(x, times, ts, W0, b0, W1, b1, batch, idx, out, ws);
}